// Round 13
// baseline (223.356 us; speedup 1.0000x reference)
//
#include <hip/hip_runtime.h>
#include <hip/hip_bf16.h>

// B=16, C=512, H=W=32 -> P=1024 pixels, 8 groups (64 ch), 8 heads (hd=64).
// Inputs f32, output f32.  Internals bf16 + fp32 accum (validated R6/R8).
// R20: fattn 4-wave blocks: q-tile 128, 256 thr, wave owns 32 q-rows
//      (2 q-frags kept).  Grid 1024 = 4 blocks/CU (LDS 34816B).  Finer
//      barrier granularity (4-wave sync) + 4 independent blocks/CU.
//      K/V single-buffered [64][64] XOR, reg-staged (write-side swizzle),
//      cross-iter reg prefetch.  Budget: LDS port was 62% busy, MFMA 18%,
//      rest = sync/latency at 2 blocks/CU -- this attacks the sync term.
// R19: gload_lds dbuf (54.0us).  R17: 2 q-frags (54.9us).
// R15: GEMMs on global_load_lds BK=64.  R14: static-max softmax p=exp2(s).
// (R10: XCD swizzle, slot-swizzle, MFMA ones row-sum, pre-scaled Q.)
#define BB   16
#define CCH  512
#define PP   1024
#define NHD  8

typedef unsigned short u16;
typedef unsigned int   u32;
typedef __attribute__((ext_vector_type(8))) short bf16x8;   // 8 bf16 = 4 VGPR
typedef __attribute__((ext_vector_type(4))) float f32x4;

__device__ __forceinline__ u16 f2bu(float f) {
    __hip_bfloat16 h = __float2bfloat16(f);   // RNE
    return *reinterpret_cast<u16*>(&h);
}

#define GLOAD_LDS16(gsrc, ldst)                                              \
    __builtin_amdgcn_global_load_lds(                                        \
        (const __attribute__((address_space(1))) u32*)(gsrc),                \
        (__attribute__((address_space(3))) u32*)(ldst), 16, 0, 0)

// ---------------------------------------------------------------------------
// Kernel 1: merged pre-pass.  Blocks 0..511: per-(bg,part) stat partials.
// Blocks 512..1535: weight f32->bf16 conversion.
// ---------------------------------------------------------------------------
__launch_bounds__(256)
__global__ void pre_k(const float* __restrict__ x,
                      float* __restrict__ ps, float* __restrict__ pss,
                      const float* __restrict__ w1, const float* __restrict__ w2,
                      u16* __restrict__ d1, u16* __restrict__ d2) {
    int blk = blockIdx.x;
    if (blk < 512) {
        int bg = blk >> 2, part = blk & 3;
        const float4* xp = (const float4*)(x + (size_t)bg * 65536 + (size_t)part * 16384);
        float s = 0.f, ss = 0.f;
        for (int i = threadIdx.x; i < 4096; i += 256) {
            float4 v = xp[i];
            s  += v.x + v.y + v.z + v.w;
            ss += v.x*v.x + v.y*v.y + v.z*v.z + v.w*v.w;
        }
        __shared__ float sh[256], sq[256];
        sh[threadIdx.x] = s; sq[threadIdx.x] = ss;
        __syncthreads();
        for (int off = 128; off > 0; off >>= 1) {
            if (threadIdx.x < off) {
                sh[threadIdx.x] += sh[threadIdx.x + off];
                sq[threadIdx.x] += sq[threadIdx.x + off];
            }
            __syncthreads();
        }
        if (threadIdx.x == 0) {
            ps[blk]  = sh[0];
            pss[blk] = sq[0];
        }
    } else {
        int id = (blk - 512) * 256 + threadIdx.x;
        const float* s; u16* d; int off;
        if (id < 196608) { s = w1; d = d1; off = id * 4; }
        else             { s = w2; d = d2; off = (id - 196608) * 4; }
        float4 v = *(const float4*)(s + off);
        ushort4 o;
        o.x = f2bu(v.x); o.y = f2bu(v.y); o.z = f2bu(v.z); o.w = f2bu(v.w);
        *(ushort4*)(d + off) = o;
    }
}

// ---------------------------------------------------------------------------
// Kernel 2: GN-normalize + convert + transpose: x[b][c][p] f32 ->
// xbt[b][p][c] bf16.  Combines the 4 stat partials (uniform -> SGPR loads).
// ---------------------------------------------------------------------------
__launch_bounds__(256)
__global__ void conv_x_k(const float* __restrict__ x,
                         const float* __restrict__ ps, const float* __restrict__ pss,
                         const float* __restrict__ gamma, const float* __restrict__ beta,
                         u16* __restrict__ xbt) {
    __shared__ u16 T[64][73];
    const int tid = threadIdx.x;
    const int p0 = blockIdx.x * 64;
    const int c0 = blockIdx.y * 64;
    const int b  = blockIdx.z;
    const int bg = (b << 3) + (c0 >> 6);      // uniform per block
    float s4  = ps[bg*4]  + ps[bg*4+1]  + ps[bg*4+2]  + ps[bg*4+3];
    float ss4 = pss[bg*4] + pss[bg*4+1] + pss[bg*4+2] + pss[bg*4+3];
    float m   = s4 * (1.f / 65536.f);
    float var = ss4 * (1.f / 65536.f) - m * m;
    float rs  = rsqrtf(var + 1e-5f);
    {
        int ci = tid >> 2, psx = (tid & 3) * 16;
        int c = c0 + ci;
        float sc = rs * gamma[c];
        float sf = beta[c] - m * sc;
        const float* xp = x + ((size_t)(b * CCH + c)) * PP + p0 + psx;
        #pragma unroll
        for (int j4 = 0; j4 < 4; j4++) {
            float4 v = *(const float4*)(xp + j4 * 4);
            T[psx + j4*4 + 0][ci] = f2bu(v.x * sc + sf);
            T[psx + j4*4 + 1][ci] = f2bu(v.y * sc + sf);
            T[psx + j4*4 + 2][ci] = f2bu(v.z * sc + sf);
            T[psx + j4*4 + 3][ci] = f2bu(v.w * sc + sf);
        }
    }
    __syncthreads();
    {
        int pi = tid >> 2, cs = (tid & 3) * 16;
        u16* dst = xbt + ((size_t)(b * PP) + p0 + pi) * CCH + c0 + cs;
        #pragma unroll
        for (int j4 = 0; j4 < 4; j4++) {
            ushort4 o;
            o.x = T[pi][cs + j4*4 + 0]; o.y = T[pi][cs + j4*4 + 1];
            o.z = T[pi][cs + j4*4 + 2]; o.w = T[pi][cs + j4*4 + 3];
            *(ushort4*)(dst + j4 * 4) = o;
        }
    }
}

// ---------------------------------------------------------------------------
// Kernel 4: qkv MFMA GEMM (R15: global_load_lds staging, BK=64, XOR swizzle).
// ---------------------------------------------------------------------------
__launch_bounds__(256)
__global__ void mgemm_qkv_k(const u16* __restrict__ Wb, const float* __restrict__ bias,
                            const u16* __restrict__ actT,
                            u16* __restrict__ qT, u16* __restrict__ kT,
                            u16* __restrict__ v) {
    __shared__ __align__(16) u16 smem[17408];    // staging 2x8192 | Cb 128x136
    u16* As = smem;                              // [128][64] swizzled
    u16* Bs = smem + 8192;
    const int tid = threadIdx.x;
    // XCD swizzle: nwg=1536, 192/XCD, 96 blocks (12m x 8p) per batch.
    const int id = blockIdx.x;
    const int wk = (id & 7) * 192 + (id >> 3);
    const int b  = wk / 96;
    const int wi = wk % 96;
    const int m0 = (wi >> 3) * 128;
    const int p0 = (wi & 7) * 128;
    const int w = tid >> 6, l = tid & 63, quad = l >> 4, lm = l & 15;
    const int mo = (w >> 1) * 64, no = (w & 1) * 64;

    f32x4 acc[4][4] = {};

    const int srow = (w << 3) + (l >> 3);
    const int scc  = ((l & 7) ^ ((l >> 3) & 7)) << 3;   // swizzled chunk, u16 units
    const u16* wp = Wb + (size_t)(m0 + srow) * CCH + scc;
    const u16* ap = actT + (size_t)b * PP * CCH + (size_t)(p0 + srow) * CCH + scc;
    const int ldsrow = ((w << 3)) * 64;                 // wave-uniform part

    const int c0a = (quad ^ (lm & 7)) << 3;             // frag chunk offset, hf=0

    for (int k0 = 0; k0 < CCH; k0 += 64) {
        #pragma unroll
        for (int is = 0; is < 4; is++) {
            GLOAD_LDS16(wp + k0 + (size_t)(is * 32) * CCH, &As[is * 2048 + ldsrow]);
            GLOAD_LDS16(ap + k0 + (size_t)(is * 32) * CCH, &Bs[is * 2048 + ldsrow]);
        }
        __syncthreads();   // drains vmcnt -> staging visible to all waves
        #pragma unroll
        for (int hf = 0; hf < 2; hf++) {
            const int cofs = hf ? (c0a ^ 32) : c0a;
            bf16x8 af[4], bfr[4];
            #pragma unroll
            for (int mi = 0; mi < 4; mi++)
                af[mi] = *(const bf16x8*)&As[(mo + mi*16 + lm) * 64 + cofs];
            #pragma unroll
            for (int ni = 0; ni < 4; ni++)
                bfr[ni] = *(const bf16x8*)&Bs[(no + ni*16 + lm) * 64 + cofs];
            __builtin_amdgcn_s_setprio(1);
            #pragma unroll
            for (int mi = 0; mi < 4; mi++)
                #pragma unroll
                for (int ni = 0; ni < 4; ni++)
                    acc[mi][ni] = __builtin_amdgcn_mfma_f32_16x16x32_bf16(
                        af[mi], bfr[ni], acc[mi][ni], 0, 0, 0);
            __builtin_amdgcn_s_setprio(0);
        }
        __syncthreads();   // protect staging before next overwrite
    }

    const int region = m0 >> 9;   // 0=Q 1=K 2=V
    if (region < 2) {
        const float scl = (region == 0) ? 0.18033688011f : 1.0f;  // 0.125*log2e
        u16* Cb = smem;
        #pragma unroll
        for (int mi = 0; mi < 4; mi++) {
            f32x4 bv = *(const f32x4*)&bias[m0 + mo + mi*16 + quad*4];
            #pragma unroll
            for (int ni = 0; ni < 4; ni++) {
                int colp = no + ni*16 + lm;
                int rowb = mo + mi*16 + quad*4;
                #pragma unroll
                for (int r = 0; r < 4; r++)
                    Cb[colp * 136 + rowb + r] = f2bu((acc[mi][ni][r] + bv[r]) * scl);
            }
        }
        __syncthreads();
        int prow = tid >> 1, half = tid & 1;
        u16* base = (region == 0) ? qT : kT;
        u16* dst = base + ((size_t)b * PP + p0 + prow) * 512 + (m0 & 511) + half * 64;
        const u16* src = &Cb[prow * 136 + half * 64];
        #pragma unroll
        for (int i = 0; i < 8; i++)
            *(uint4*)(dst + i * 8) = *(const uint4*)(src + i * 8);
    } else {
        u16* Cb = smem;
        #pragma unroll
        for (int mi = 0; mi < 4; mi++) {
            f32x4 bv = *(const f32x4*)&bias[m0 + mo + mi*16 + quad*4];
            #pragma unroll
            for (int ni = 0; ni < 4; ni++) {
                int colp = no + ni*16 + lm;
                int rowb = mo + mi*16 + quad*4;
                #pragma unroll
                for (int r = 0; r < 4; r++)
                    Cb[(rowb + r) * 136 + colp] = f2bu(acc[mi][ni][r] + bv[r]);
            }
        }
        __syncthreads();
        int row = tid >> 1, half = tid & 1;
        u16* dst = v + ((size_t)b * 512 + (m0 - 1024) + row) * PP + p0 + half * 64;
        const u16* src = &Cb[row * 136 + half * 64];
        #pragma unroll
        for (int i = 0; i < 8; i++)
            *(uint4*)(dst + i * 8) = *(const uint4*)(src + i * 8);
    }
}

// ---------------------------------------------------------------------------
// Kernel 5: MFMA flash attention.  R20: 4-wave blocks, q-tile 128, wave owns
// 32 q-rows (2 q-frags).  Grid 1024 = 4 blocks/CU.
//   Ps [128][72] u16 : per-wave 32-row P region + O epilogue   18432 B
//   Ks [ 64][64] u16 : XOR-swizzled (write side)                8192 B
//   Vs [ 64][64] u16 : XOR-swizzled                             8192 B
//   total 34816 B -> 4 blocks/CU.
// K/V reg-staged single-buffer, cross-iter prefetch; 2 barriers/iter over
// only 4 waves.  Static-max softmax (R14): p = exp2(s), no reduction.
// ---------------------------------------------------------------------------
__launch_bounds__(256, 4)
__global__ void fattn_k(const u16* __restrict__ qT, const u16* __restrict__ kT,
                        const u16* __restrict__ v, u16* __restrict__ ao) {
    __shared__ __align__(16) u16 Ps[128 * 72];
    __shared__ __align__(16) u16 Ks[64 * 64];
    __shared__ __align__(16) u16 Vs[64 * 64];
    const int tid = threadIdx.x;
    // XCD swizzle: nwg=1024, 128/XCD, (b,h) pair = 8 consecutive work units.
    const int id = blockIdx.x;
    const int wk = ((id & 7) << 7) | (id >> 3);
    const int q0 = (wk & 7) * 128;
    const int pair = wk >> 3;
    const int h = pair & 7;
    const int b = pair >> 3;
    const int w = tid >> 6, l = tid & 63, quad = l >> 4, lm = l & 15;
    const int psw = ((lm >> 2) & 3) << 4;      // Ps slot unswizzle key

    // Q direct from global: frag A rows w*32+lm, frag B rows w*32+16+lm
    bf16x8 qf0a, qf1a, qf0b, qf1b;
    {
        const u16* qsrc = qT + ((size_t)b * PP + q0 + w * 32 + lm) * 512 + h * 64 + quad * 8;
        qf0a = *(const bf16x8*)qsrc;
        qf1a = *(const bf16x8*)(qsrc + 32);
        qf0b = *(const bf16x8*)(qsrc + 16 * 512);
        qf1b = *(const bf16x8*)(qsrc + 16 * 512 + 32);
    }

    bf16x8 onesv;
    #pragma unroll
    for (int i = 0; i < 8; i++) onesv[i] = (short)0x3F80;   // bf16 1.0

    f32x4 Oa[4] = {}, Ob[4] = {};
    f32x4 Ola = {}, Olb = {};                   // ones-column row sums

    // staging: thread t -> row t>>2 (0..63), granule pair g0=(t&3)*2, g0+1;
    // LDS granule swizzled g^(row&7); global loads LINEAR chunks (coalesced).
    const int srow = tid >> 2;
    const int g0   = (tid & 3) * 2;
    const int sg0  = (g0 ^ (srow & 7)) << 3;         // u16 offset in row
    const int sg1  = ((g0 + 1) ^ (srow & 7)) << 3;
    const u16* kgb = kT + ((size_t)b * PP + srow) * 512 + h * 64 + g0 * 8;
    const u16* vgb = v + ((size_t)b * 512 + h * 64 + srow) * PP + g0 * 8;

    // fragment-read swizzled chunk offsets (row&7 == lm&7 for rows ni*16+lm)
    const int kroA = (quad ^ (lm & 7)) << 3;         // K chunks 0..3 (k=0..31)
    const int kroB = kroA ^ 32;                      // K chunks 4..7 (k=32..63)

    // prologue: load tile 0 into regs
    uint4 ka0, ka1, va0, va1;
    ka0 = *(const uint4*)kgb;        ka1 = *(const uint4*)(kgb + 8);
    va0 = *(const uint4*)vgb;        va1 = *(const uint4*)(vgb + 8);

    for (int j0 = 0; j0 < PP; j0 += 64) {
        __syncthreads();   // previous iter's Ks/Vs reads done
        *(uint4*)&Ks[srow * 64 + sg0] = ka0;
        *(uint4*)&Ks[srow * 64 + sg1] = ka1;
        *(uint4*)&Vs[srow * 64 + sg0] = va0;
        *(uint4*)&Vs[srow * 64 + sg1] = va1;
        __syncthreads();   // staging visible to all waves

        if (j0 + 64 < PP) {                          // prefetch tile t+1
            const u16* kp = kgb + (size_t)(j0 + 64) * 512;
            ka0 = *(const uint4*)kp;  ka1 = *(const uint4*)(kp + 8);
            const u16* vp = vgb + (j0 + 64);
            va0 = *(const uint4*)vp;  va1 = *(const uint4*)(vp + 8);
        }

        // S = Q.K^T : 4 j-subtiles x (k=64 -> 2 MFMAs) x 2 q-frags.
        f32x4 sa[4], sb[4];
        __builtin_amdgcn_s_setprio(1);
        #pragma unroll
        for (int ni = 0; ni < 4; ni++) {
            bf16x8 kf0 = *(const bf16x8*)&Ks[(ni*16 + lm) * 64 + kroA];
            bf16x8 kf1 = *(const bf16x8*)&Ks[(ni*16 + lm) * 64 + kroB];
            f32x4 za = {}, zb = {};
            za = __builtin_amdgcn_mfma_f32_16x16x32_bf16(qf0a, kf0, za, 0, 0, 0);
            sa[ni] = __builtin_amdgcn_mfma_f32_16x16x32_bf16(qf1a, kf1, za, 0, 0, 0);
            zb = __builtin_amdgcn_mfma_f32_16x16x32_bf16(qf0b, kf0, zb, 0, 0, 0);
            sb[ni] = __builtin_amdgcn_mfma_f32_16x16x32_bf16(qf1b, kf1, zb, 0, 0, 0);
        }
        __builtin_amdgcn_s_setprio(0);

        // static-max softmax: p = exp2(s), elementwise (exp2 domain already).
        // P -> per-wave Ps region (slot-swizzled: col = lm + 16*(ni^quad)).
        #pragma unroll
        for (int r = 0; r < 4; r++) {
            int rowa = (w * 32 + quad * 4 + r) * 72 + lm;
            int rowb_ = (w * 32 + 16 + quad * 4 + r) * 72 + lm;
            #pragma unroll
            for (int ni = 0; ni < 4; ni++) {
                Ps[rowa  + 16 * (ni ^ quad)] = f2bu(__builtin_amdgcn_exp2f(sa[ni][r]));
                Ps[rowb_ + 16 * (ni ^ quad)] = f2bu(__builtin_amdgcn_exp2f(sb[ni][r]));
            }
        }
        // no barrier: P write/read is wave-local, DS in-order

        // O += P.V : 2 k-frags (j) x 4 d-subtiles x 2 q-frags.
        __builtin_amdgcn_s_setprio(1);
        #pragma unroll
        for (int kf = 0; kf < 2; kf++) {
            bf16x8 pfa = *(const bf16x8*)&Ps[(w*32 + lm) * 72 + ((kf * 32 + quad * 8) ^ psw)];
            bf16x8 pfb = *(const bf16x8*)&Ps[(w*32 + 16 + lm) * 72 + ((kf * 32 + quad * 8) ^ psw)];
            Ola = __builtin_amdgcn_mfma_f32_16x16x32_bf16(pfa, onesv, Ola, 0, 0, 0);
            Olb = __builtin_amdgcn_mfma_f32_16x16x32_bf16(pfb, onesv, Olb, 0, 0, 0);
            #pragma unroll
            for (int nd = 0; nd < 4; nd++) {
                int vro = (((kf << 2) | quad) ^ (lm & 7)) << 3;
                bf16x8 vf = *(const bf16x8*)&Vs[(nd*16 + lm) * 64 + vro];
                Oa[nd] = __builtin_amdgcn_mfma_f32_16x16x32_bf16(pfa, vf, Oa[nd], 0, 0, 0);
                Ob[nd] = __builtin_amdgcn_mfma_f32_16x16x32_bf16(pfb, vf, Ob[nd], 0, 0, 0);
            }
        }
        __builtin_amdgcn_s_setprio(0);
    }

    // epilogue (wave-local): normalize, O -> Ps [q][d] (slot-swizzled), store
    #pragma unroll
    for (int r = 0; r < 4; r++) {
        float ra = 1.f / Ola[r];
        float rb = 1.f / Olb[r];
        int rowa = (w * 32 + quad * 4 + r) * 72 + lm;
        int rowb_ = (w * 32 + 16 + quad * 4 + r) * 72 + lm;
        #pragma unroll
        for (int nd = 0; nd < 4; nd++) {
            Ps[rowa  + 16 * (nd ^ quad)] = f2bu(Oa[nd][r] * ra);
            Ps[rowb_ + 16 * (nd ^ quad)] = f2bu(Ob[nd][r] * rb);
        }
    }
    {
        // 2 lanes per row of the wave's 32 rows; each lane stores its full
        // 32-u16 half-row (slots g0q, g0q+1), unswizzled by the row's quad.
        int rr  = w * 32 + (l >> 1);
        int key = (l >> 3) & 3;                // == ((rr & 15) >> 2)
        int g0q = 2 * (l & 1);
        u16* dst = ao + ((size_t)b * PP + q0 + rr) * 512 + h * 64 + (l & 1) * 32;
        const u16* s0 = &Ps[rr * 72 + 16 * (g0q ^ key)];
        const u16* s1 = &Ps[rr * 72 + 16 * ((g0q + 1) ^ key)];
        *(uint4*)(dst + 0)  = *(const uint4*)(s0);
        *(uint4*)(dst + 8)  = *(const uint4*)(s0 + 8);
        *(uint4*)(dst + 16) = *(const uint4*)(s1);
        *(uint4*)(dst + 24) = *(const uint4*)(s1 + 8);
    }
}

// ---------------------------------------------------------------------------
// Kernel 6: out-proj MFMA GEMM + bias + residual, f32 out (R15 staging).
// ---------------------------------------------------------------------------
__launch_bounds__(256)
__global__ void mgemm_out_k(const u16* __restrict__ Wb, const float* __restrict__ bias,
                            const u16* __restrict__ actT, const float* __restrict__ resid,
                            float* __restrict__ out) {
    __shared__ __align__(16) u16 smem[16384];    // staging 2x8192
    u16* As = smem;                              // [128][64] swizzled
    u16* Bs = smem + 8192;
    const int tid = threadIdx.x;
    // XCD swizzle: nwg=512, 64/XCD, 32 blocks (4m x 8p) per batch.
    const int id = blockIdx.x;
    const int wk = (id & 7) * 64 + (id >> 3);
    const int b  = wk >> 5;
    const int wi = wk & 31;
    const int m0 = (wi >> 3) * 128;
    const int p0 = (wi & 7) * 128;
    const int w = tid >> 6, l = tid & 63, quad = l >> 4, lm = l & 15;
    const int mo = (w >> 1) * 64, no = (w & 1) * 64;

    f32x4 acc[4][4] = {};

    const int srow = (w << 3) + (l >> 3);
    const int scc  = ((l & 7) ^ ((l >> 3) & 7)) << 3;
    const u16* wp = Wb + (size_t)(m0 + srow) * CCH + scc;
    const u16* ap = actT + (size_t)b * PP * CCH + (size_t)(p0 + srow) * CCH + scc;
    const int ldsrow = ((w << 3)) * 64;

    const int c0a = (quad ^ (lm & 7)) << 3;

    for (int k0 = 0; k0 < CCH; k0 += 64) {
        #pragma unroll
        for (int is = 0; is < 4; is++) {
            GLOAD_LDS16(wp + k0 + (size_t)(is * 32) * CCH, &As[is * 2048 + ldsrow]);
            GLOAD_LDS16(ap + k0 + (size_t)(is * 32) * CCH, &Bs[is * 2048 + ldsrow]);
        }
        __syncthreads();
        #pragma unroll
        for (int hf = 0; hf < 2; hf++) {
            const int cofs = hf ? (c0a ^ 32) : c0a;
            bf16x8 af[4], bfr[4];
            #pragma unroll
            for (int mi = 0; mi < 4; mi++)
                af[mi] = *(const bf16x8*)&As[(mo + mi*16 + lm) * 64 + cofs];
            #pragma unroll
            for (int ni = 0; ni < 4; ni++)
                bfr[ni] = *(const bf16x8*)&Bs[(no + ni*16 + lm) * 64 + cofs];
            __builtin_amdgcn_s_setprio(1);
            #pragma unroll
            for (int mi = 0; mi < 4; mi++)
                #pragma unroll
                for (int ni = 0; ni < 4; ni++)
                    acc[mi][ni] = __builtin_amdgcn_mfma_f32_16x16x32_bf16(
                        af[mi], bfr[ni], acc[mi][ni], 0, 0, 0);
            __builtin_amdgcn_s_setprio(0);
        }
        __syncthreads();
    }

    #pragma unroll
    for (int mi = 0; mi < 4; mi++) {
        f32x4 bv = *(const f32x4*)&bias[m0 + mo + mi*16 + quad*4];
        #pragma unroll
        for (int ni = 0; ni < 4; ni++) {
            int p = p0 + no + ni*16 + lm;
            #pragma unroll
            for (int r = 0; r < 4; r++) {
                int m = m0 + mo + mi*16 + quad*4 + r;
                size_t idx = ((size_t)b * CCH + m) * PP + p;
                out[idx] = acc[mi][ni][r] + bv[r] + resid[idx];
            }
        }
    }
}

// ---------------------------------------------------------------------------
extern "C" void kernel_launch(void* const* d_in, const int* in_sizes, int n_in,
                              void* d_out, int out_size, void* d_ws, size_t ws_size,
                              hipStream_t stream) {
    const float* x     = (const float*)d_in[0];
    const float* gamma = (const float*)d_in[1];
    const float* beta  = (const float*)d_in[2];
    const float* w_qkv = (const float*)d_in[3];
    const float* b_qkv = (const float*)d_in[4];
    const float* w_out = (const float*)d_in[5];
    const float* b_out = (const float*)d_in[6];

    char* ws = (char*)d_ws;
    float* ps  = (float*)ws;                    // 512 f32 partial sums
    float* pss = (float*)(ws + 2048);           // 512 f32 partial sumsq
    u16* wqb = (u16*)(ws + 4096);               // 1536*512
    u16* wob = wqb + 1536 * 512;                // 512*512
    u16* xbt = wob + 512 * 512;                 // [b][p][c]  8.4M elems
    u16* ao  = xbt + (size_t)BB * PP * CCH;     // [b][p][c]  8.4M
    u16* qTb = ao  + (size_t)BB * PP * CCH;     // [b][p][512] 8.4M
    u16* kTb = qTb + (size_t)BB * PP * CCH;     // [b][p][512] 8.4M
    u16* vb  = kTb + (size_t)BB * PP * CCH;     // [b][512][p] 8.4M  (~86 MB)

    pre_k<<<1536, 256, 0, stream>>>(x, ps, pss, w_qkv, w_out, wqb, wob);
    conv_x_k<<<dim3(16, 8, 16), 256, 0, stream>>>(x, ps, pss, gamma, beta, xbt);
    mgemm_qkv_k<<<1536, 256, 0, stream>>>(wqb, b_qkv, xbt, qTb, kTb, vb);
    fattn_k<<<1024, 256, 0, stream>>>(qTb, kTb, vb, ao);
    mgemm_out_k<<<512, 256, 0, stream>>>(wob, b_out, ao, x, (float*)d_out);
}

// Round 14
// 213.855 us; speedup vs baseline: 1.0444x; 1.0444x over previous
//
#include <hip/hip_runtime.h>
#include <hip/hip_bf16.h>

// B=16, C=512, H=W=32 -> P=1024 pixels, 8 groups (64 ch), 8 heads (hd=64).
// Inputs f32, output f32.  Internals bf16 + fp32 accum (validated R6/R8).
// R21: revert R20 (4-wave split regressed: 2x staging, no occupancy gain).
//      fattn = R19 structure + T12 SWAPPED QK^T: S^T = mfma(K,Q) puts
//      P[q=lm][j=ni*16+quad*4+r] lane-local with r-contiguous cols ->
//      P stored as 8x ds_write_b64 instead of 64x ds_write_b16 (8x fewer
//      LDS ops).  Q registers serve as B-operand unchanged; K LDS reads
//      unchanged; PV + epilogue unchanged; slot-swizzle machinery deleted
//      (plain [q][j] / [q][d] Ps layout, 2-way-free banks at stride 144B).
// R19: gload_lds K/V dbuf, 1 barrier/iter (54.0us).  R17: 2 q-frags/wave.
// R15: GEMMs on global_load_lds BK=64.  R14: static-max softmax p=exp2(s).
// (R10: XCD swizzle, MFMA ones row-sum, pre-scaled Q.)
#define BB   16
#define CCH  512
#define PP   1024
#define NHD  8

typedef unsigned short u16;
typedef unsigned int   u32;
typedef __attribute__((ext_vector_type(8))) short bf16x8;   // 8 bf16 = 4 VGPR
typedef __attribute__((ext_vector_type(4))) float f32x4;

__device__ __forceinline__ u16 f2bu(float f) {
    __hip_bfloat16 h = __float2bfloat16(f);   // RNE
    return *reinterpret_cast<u16*>(&h);
}

#define GLOAD_LDS16(gsrc, ldst)                                              \
    __builtin_amdgcn_global_load_lds(                                        \
        (const __attribute__((address_space(1))) u32*)(gsrc),                \
        (__attribute__((address_space(3))) u32*)(ldst), 16, 0, 0)

// ---------------------------------------------------------------------------
// Kernel 1: merged pre-pass.  Blocks 0..511: per-(bg,part) stat partials.
// Blocks 512..1535: weight f32->bf16 conversion.
// ---------------------------------------------------------------------------
__launch_bounds__(256)
__global__ void pre_k(const float* __restrict__ x,
                      float* __restrict__ ps, float* __restrict__ pss,
                      const float* __restrict__ w1, const float* __restrict__ w2,
                      u16* __restrict__ d1, u16* __restrict__ d2) {
    int blk = blockIdx.x;
    if (blk < 512) {
        int bg = blk >> 2, part = blk & 3;
        const float4* xp = (const float4*)(x + (size_t)bg * 65536 + (size_t)part * 16384);
        float s = 0.f, ss = 0.f;
        for (int i = threadIdx.x; i < 4096; i += 256) {
            float4 v = xp[i];
            s  += v.x + v.y + v.z + v.w;
            ss += v.x*v.x + v.y*v.y + v.z*v.z + v.w*v.w;
        }
        __shared__ float sh[256], sq[256];
        sh[threadIdx.x] = s; sq[threadIdx.x] = ss;
        __syncthreads();
        for (int off = 128; off > 0; off >>= 1) {
            if (threadIdx.x < off) {
                sh[threadIdx.x] += sh[threadIdx.x + off];
                sq[threadIdx.x] += sq[threadIdx.x + off];
            }
            __syncthreads();
        }
        if (threadIdx.x == 0) {
            ps[blk]  = sh[0];
            pss[blk] = sq[0];
        }
    } else {
        int id = (blk - 512) * 256 + threadIdx.x;
        const float* s; u16* d; int off;
        if (id < 196608) { s = w1; d = d1; off = id * 4; }
        else             { s = w2; d = d2; off = (id - 196608) * 4; }
        float4 v = *(const float4*)(s + off);
        ushort4 o;
        o.x = f2bu(v.x); o.y = f2bu(v.y); o.z = f2bu(v.z); o.w = f2bu(v.w);
        *(ushort4*)(d + off) = o;
    }
}

// ---------------------------------------------------------------------------
// Kernel 2: GN-normalize + convert + transpose: x[b][c][p] f32 ->
// xbt[b][p][c] bf16.  Combines the 4 stat partials (uniform -> SGPR loads).
// ---------------------------------------------------------------------------
__launch_bounds__(256)
__global__ void conv_x_k(const float* __restrict__ x,
                         const float* __restrict__ ps, const float* __restrict__ pss,
                         const float* __restrict__ gamma, const float* __restrict__ beta,
                         u16* __restrict__ xbt) {
    __shared__ u16 T[64][73];
    const int tid = threadIdx.x;
    const int p0 = blockIdx.x * 64;
    const int c0 = blockIdx.y * 64;
    const int b  = blockIdx.z;
    const int bg = (b << 3) + (c0 >> 6);      // uniform per block
    float s4  = ps[bg*4]  + ps[bg*4+1]  + ps[bg*4+2]  + ps[bg*4+3];
    float ss4 = pss[bg*4] + pss[bg*4+1] + pss[bg*4+2] + pss[bg*4+3];
    float m   = s4 * (1.f / 65536.f);
    float var = ss4 * (1.f / 65536.f) - m * m;
    float rs  = rsqrtf(var + 1e-5f);
    {
        int ci = tid >> 2, psx = (tid & 3) * 16;
        int c = c0 + ci;
        float sc = rs * gamma[c];
        float sf = beta[c] - m * sc;
        const float* xp = x + ((size_t)(b * CCH + c)) * PP + p0 + psx;
        #pragma unroll
        for (int j4 = 0; j4 < 4; j4++) {
            float4 v = *(const float4*)(xp + j4 * 4);
            T[psx + j4*4 + 0][ci] = f2bu(v.x * sc + sf);
            T[psx + j4*4 + 1][ci] = f2bu(v.y * sc + sf);
            T[psx + j4*4 + 2][ci] = f2bu(v.z * sc + sf);
            T[psx + j4*4 + 3][ci] = f2bu(v.w * sc + sf);
        }
    }
    __syncthreads();
    {
        int pi = tid >> 2, cs = (tid & 3) * 16;
        u16* dst = xbt + ((size_t)(b * PP) + p0 + pi) * CCH + c0 + cs;
        #pragma unroll
        for (int j4 = 0; j4 < 4; j4++) {
            ushort4 o;
            o.x = T[pi][cs + j4*4 + 0]; o.y = T[pi][cs + j4*4 + 1];
            o.z = T[pi][cs + j4*4 + 2]; o.w = T[pi][cs + j4*4 + 3];
            *(ushort4*)(dst + j4 * 4) = o;
        }
    }
}

// ---------------------------------------------------------------------------
// Kernel 4: qkv MFMA GEMM (R15: global_load_lds staging, BK=64, XOR swizzle).
// ---------------------------------------------------------------------------
__launch_bounds__(256)
__global__ void mgemm_qkv_k(const u16* __restrict__ Wb, const float* __restrict__ bias,
                            const u16* __restrict__ actT,
                            u16* __restrict__ qT, u16* __restrict__ kT,
                            u16* __restrict__ v) {
    __shared__ __align__(16) u16 smem[17408];    // staging 2x8192 | Cb 128x136
    u16* As = smem;                              // [128][64] swizzled
    u16* Bs = smem + 8192;
    const int tid = threadIdx.x;
    // XCD swizzle: nwg=1536, 192/XCD, 96 blocks (12m x 8p) per batch.
    const int id = blockIdx.x;
    const int wk = (id & 7) * 192 + (id >> 3);
    const int b  = wk / 96;
    const int wi = wk % 96;
    const int m0 = (wi >> 3) * 128;
    const int p0 = (wi & 7) * 128;
    const int w = tid >> 6, l = tid & 63, quad = l >> 4, lm = l & 15;
    const int mo = (w >> 1) * 64, no = (w & 1) * 64;

    f32x4 acc[4][4] = {};

    const int srow = (w << 3) + (l >> 3);
    const int scc  = ((l & 7) ^ ((l >> 3) & 7)) << 3;   // swizzled chunk, u16 units
    const u16* wp = Wb + (size_t)(m0 + srow) * CCH + scc;
    const u16* ap = actT + (size_t)b * PP * CCH + (size_t)(p0 + srow) * CCH + scc;
    const int ldsrow = ((w << 3)) * 64;                 // wave-uniform part

    const int c0a = (quad ^ (lm & 7)) << 3;             // frag chunk offset, hf=0

    for (int k0 = 0; k0 < CCH; k0 += 64) {
        #pragma unroll
        for (int is = 0; is < 4; is++) {
            GLOAD_LDS16(wp + k0 + (size_t)(is * 32) * CCH, &As[is * 2048 + ldsrow]);
            GLOAD_LDS16(ap + k0 + (size_t)(is * 32) * CCH, &Bs[is * 2048 + ldsrow]);
        }
        __syncthreads();   // drains vmcnt -> staging visible to all waves
        #pragma unroll
        for (int hf = 0; hf < 2; hf++) {
            const int cofs = hf ? (c0a ^ 32) : c0a;
            bf16x8 af[4], bfr[4];
            #pragma unroll
            for (int mi = 0; mi < 4; mi++)
                af[mi] = *(const bf16x8*)&As[(mo + mi*16 + lm) * 64 + cofs];
            #pragma unroll
            for (int ni = 0; ni < 4; ni++)
                bfr[ni] = *(const bf16x8*)&Bs[(no + ni*16 + lm) * 64 + cofs];
            __builtin_amdgcn_s_setprio(1);
            #pragma unroll
            for (int mi = 0; mi < 4; mi++)
                #pragma unroll
                for (int ni = 0; ni < 4; ni++)
                    acc[mi][ni] = __builtin_amdgcn_mfma_f32_16x16x32_bf16(
                        af[mi], bfr[ni], acc[mi][ni], 0, 0, 0);
            __builtin_amdgcn_s_setprio(0);
        }
        __syncthreads();   // protect staging before next overwrite
    }

    const int region = m0 >> 9;   // 0=Q 1=K 2=V
    if (region < 2) {
        const float scl = (region == 0) ? 0.18033688011f : 1.0f;  // 0.125*log2e
        u16* Cb = smem;
        #pragma unroll
        for (int mi = 0; mi < 4; mi++) {
            f32x4 bv = *(const f32x4*)&bias[m0 + mo + mi*16 + quad*4];
            #pragma unroll
            for (int ni = 0; ni < 4; ni++) {
                int colp = no + ni*16 + lm;
                int rowb = mo + mi*16 + quad*4;
                #pragma unroll
                for (int r = 0; r < 4; r++)
                    Cb[colp * 136 + rowb + r] = f2bu((acc[mi][ni][r] + bv[r]) * scl);
            }
        }
        __syncthreads();
        int prow = tid >> 1, half = tid & 1;
        u16* base = (region == 0) ? qT : kT;
        u16* dst = base + ((size_t)b * PP + p0 + prow) * 512 + (m0 & 511) + half * 64;
        const u16* src = &Cb[prow * 136 + half * 64];
        #pragma unroll
        for (int i = 0; i < 8; i++)
            *(uint4*)(dst + i * 8) = *(const uint4*)(src + i * 8);
    } else {
        u16* Cb = smem;
        #pragma unroll
        for (int mi = 0; mi < 4; mi++) {
            f32x4 bv = *(const f32x4*)&bias[m0 + mo + mi*16 + quad*4];
            #pragma unroll
            for (int ni = 0; ni < 4; ni++) {
                int colp = no + ni*16 + lm;
                int rowb = mo + mi*16 + quad*4;
                #pragma unroll
                for (int r = 0; r < 4; r++)
                    Cb[(rowb + r) * 136 + colp] = f2bu(acc[mi][ni][r] + bv[r]);
            }
        }
        __syncthreads();
        int row = tid >> 1, half = tid & 1;
        u16* dst = v + ((size_t)b * 512 + (m0 - 1024) + row) * PP + p0 + half * 64;
        const u16* src = &Cb[row * 136 + half * 64];
        #pragma unroll
        for (int i = 0; i < 8; i++)
            *(uint4*)(dst + i * 8) = *(const uint4*)(src + i * 8);
    }
}

// ---------------------------------------------------------------------------
// Kernel 5: MFMA flash attention.  R21: R19 structure + swapped QK^T.
//   8 waves, q-tile 256, wave owns 32 q-rows (2 q-frags); KVBLK=64;
//   K/V via global_load_lds double-buffer (1 barrier/iter);
//   SWAPPED QK: S^T = mfma(kf, qf) -> lane holds P[q=lm][j=16ni+4quad+r],
//   packed ds_write_b64 P-store; Ps layout PLAIN [q][72] (no swizzle).
//   Ps [256][72] 36864 B | Ks 2x[64][64] 16384 B | Vs 2x[64][64] 16384 B
//   = 69632 B -> 2 blocks/CU.  Static-max softmax p=exp2(s).
// ---------------------------------------------------------------------------
__launch_bounds__(512, 4)
__global__ void fattn_k(const u16* __restrict__ qT, const u16* __restrict__ kT,
                        const u16* __restrict__ v, u16* __restrict__ ao) {
    __shared__ __align__(16) u16 Ps[256 * 72];
    __shared__ __align__(16) u16 Ks[2][64 * 64];
    __shared__ __align__(16) u16 Vs[2][64 * 64];
    const int tid = threadIdx.x;
    // XCD swizzle: nwg=512, 64/XCD, (b,h) pair = 4 consecutive work units.
    const int id = blockIdx.x;
    const int wk = ((id & 7) << 6) | (id >> 3);
    const int q0 = (wk & 3) * 256;
    const int pair = wk >> 2;
    const int h = pair & 7;
    const int b = pair >> 3;
    const int w = tid >> 6, l = tid & 63, quad = l >> 4, lm = l & 15;

    // Q direct from global: frag A rows w*32+lm, frag B rows w*32+16+lm
    bf16x8 qf0a, qf1a, qf0b, qf1b;
    {
        const u16* qsrc = qT + ((size_t)b * PP + q0 + w * 32 + lm) * 512 + h * 64 + quad * 8;
        qf0a = *(const bf16x8*)qsrc;
        qf1a = *(const bf16x8*)(qsrc + 32);
        qf0b = *(const bf16x8*)(qsrc + 16 * 512);
        qf1b = *(const bf16x8*)(qsrc + 16 * 512 + 32);
    }

    bf16x8 onesv;
    #pragma unroll
    for (int i = 0; i < 8; i++) onesv[i] = (short)0x3F80;   // bf16 1.0

    f32x4 Oa[4] = {}, Ob[4] = {};
    f32x4 Ola = {}, Olb = {};                   // ones-column row sums

    // staging: wave w owns rows w*8..w*8+7; lane l -> row w*8+(l>>3),
    // swizzled chunk (l&7)^(l>>3); LDS dest linear = base(w*512) + lane*16B.
    const int ssr = l >> 3;                          // sub-row 0..7
    const int scc = ((l & 7) ^ ssr) << 3;            // swizzled chunk, u16
    const u16* kgb = kT + ((size_t)b * PP + w * 8 + ssr) * 512 + h * 64 + scc;
    const u16* vgb = v + ((size_t)b * 512 + h * 64 + w * 8 + ssr) * PP + scc;
    const int ldsb = w * 512;                        // wave-uniform LDS base

    // K fragment-read swizzled chunk offsets (row&7 == lm&7)
    const int kroA = (quad ^ (lm & 7)) << 3;         // K chunks 0..3 (k=0..31)
    const int kroB = kroA ^ 32;                      // K chunks 4..7 (k=32..63)

    // P rows for this lane (plain layout)
    const int prowA = (w * 32 + lm) * 72;
    const int prowB = (w * 32 + 16 + lm) * 72;

    // prologue: stage tile 0
    GLOAD_LDS16(kgb, &Ks[0][ldsb]);
    GLOAD_LDS16(vgb, &Vs[0][ldsb]);
    int cur = 0;

    for (int j0 = 0; j0 < PP; j0 += 64) {
        __syncthreads();   // implicit vmcnt drain: Ks/Vs[cur] staged+visible
        if (j0 + 64 < PP) {                          // prefetch tile t+1
            GLOAD_LDS16(kgb + (size_t)(j0 + 64) * 512, &Ks[cur ^ 1][ldsb]);
            GLOAD_LDS16(vgb + (j0 + 64), &Vs[cur ^ 1][ldsb]);
        }

        // S^T = K.Q^T (swapped): lane holds S[j=16ni+4quad+r][q=lm] ==
        // P[q=lm][j] values for its own q-row.  K = A-operand (LDS),
        // Q registers = B-operand (same bits as old A-frag).
        f32x4 sa[4], sb[4];
        __builtin_amdgcn_s_setprio(1);
        #pragma unroll
        for (int ni = 0; ni < 4; ni++) {
            bf16x8 kf0 = *(const bf16x8*)&Ks[cur][(ni*16 + lm) * 64 + kroA];
            bf16x8 kf1 = *(const bf16x8*)&Ks[cur][(ni*16 + lm) * 64 + kroB];
            f32x4 za = {}, zb = {};
            za = __builtin_amdgcn_mfma_f32_16x16x32_bf16(kf0, qf0a, za, 0, 0, 0);
            sa[ni] = __builtin_amdgcn_mfma_f32_16x16x32_bf16(kf1, qf1a, za, 0, 0, 0);
            zb = __builtin_amdgcn_mfma_f32_16x16x32_bf16(kf0, qf0b, zb, 0, 0, 0);
            sb[ni] = __builtin_amdgcn_mfma_f32_16x16x32_bf16(kf1, qf1b, zb, 0, 0, 0);
        }
        __builtin_amdgcn_s_setprio(0);

        // static-max softmax: p = exp2(s) (exp2 domain already).
        // Packed P-store: 4 r-contiguous cols -> one ds_write_b64 per ni.
        #pragma unroll
        for (int ni = 0; ni < 4; ni++) {
            ushort4 pka, pkb;
            pka.x = f2bu(__builtin_amdgcn_exp2f(sa[ni][0]));
            pka.y = f2bu(__builtin_amdgcn_exp2f(sa[ni][1]));
            pka.z = f2bu(__builtin_amdgcn_exp2f(sa[ni][2]));
            pka.w = f2bu(__builtin_amdgcn_exp2f(sa[ni][3]));
            pkb.x = f2bu(__builtin_amdgcn_exp2f(sb[ni][0]));
            pkb.y = f2bu(__builtin_amdgcn_exp2f(sb[ni][1]));
            pkb.z = f2bu(__builtin_amdgcn_exp2f(sb[ni][2]));
            pkb.w = f2bu(__builtin_amdgcn_exp2f(sb[ni][3]));
            *(ushort4*)&Ps[prowA + ni * 16 + quad * 4] = pka;
            *(ushort4*)&Ps[prowB + ni * 16 + quad * 4] = pkb;
        }
        // no barrier: P write/read is wave-local, DS in-order

        // O += P.V : 2 k-frags (j) x 4 d-subtiles x 2 q-frags.
        __builtin_amdgcn_s_setprio(1);
        #pragma unroll
        for (int kf = 0; kf < 2; kf++) {
            bf16x8 pfa = *(const bf16x8*)&Ps[prowA + kf * 32 + quad * 8];
            bf16x8 pfb = *(const bf16x8*)&Ps[prowB + kf * 32 + quad * 8];
            Ola = __builtin_amdgcn_mfma_f32_16x16x32_bf16(pfa, onesv, Ola, 0, 0, 0);
            Olb = __builtin_amdgcn_mfma_f32_16x16x32_bf16(pfb, onesv, Olb, 0, 0, 0);
            #pragma unroll
            for (int nd = 0; nd < 4; nd++) {
                int vro = (((kf << 2) | quad) ^ (lm & 7)) << 3;
                bf16x8 vf = *(const bf16x8*)&Vs[cur][(nd*16 + lm) * 64 + vro];
                Oa[nd] = __builtin_amdgcn_mfma_f32_16x16x32_bf16(pfa, vf, Oa[nd], 0, 0, 0);
                Ob[nd] = __builtin_amdgcn_mfma_f32_16x16x32_bf16(pfb, vf, Ob[nd], 0, 0, 0);
            }
        }
        __builtin_amdgcn_s_setprio(0);
        cur ^= 1;
    }

    // epilogue (wave-local): normalize, O -> Ps [q][d] (PLAIN), store
    #pragma unroll
    for (int r = 0; r < 4; r++) {
        float ra = 1.f / Ola[r];
        float rb = 1.f / Olb[r];
        int rowa = (w * 32 + quad * 4 + r) * 72;
        int rowb_ = (w * 32 + 16 + quad * 4 + r) * 72;
        #pragma unroll
        for (int nd = 0; nd < 4; nd++) {
            Ps[rowa  + nd * 16 + lm] = f2bu(Oa[nd][r] * ra);
            Ps[rowb_ + nd * 16 + lm] = f2bu(Ob[nd][r] * rb);
        }
    }
    {
        // 2 lanes per row; each lane stores its 32-u16 half-row (plain).
        int rr  = w * 32 + (l >> 1);
        u16* dst = ao + ((size_t)b * PP + q0 + rr) * 512 + h * 64 + (l & 1) * 32;
        const u16* s0 = &Ps[rr * 72 + (l & 1) * 32];
        *(uint4*)(dst + 0)  = *(const uint4*)(s0);
        *(uint4*)(dst + 8)  = *(const uint4*)(s0 + 8);
        *(uint4*)(dst + 16) = *(const uint4*)(s0 + 16);
        *(uint4*)(dst + 24) = *(const uint4*)(s0 + 24);
    }
}

// ---------------------------------------------------------------------------
// Kernel 6: out-proj MFMA GEMM + bias + residual, f32 out (R15 staging).
// ---------------------------------------------------------------------------
__launch_bounds__(256)
__global__ void mgemm_out_k(const u16* __restrict__ Wb, const float* __restrict__ bias,
                            const u16* __restrict__ actT, const float* __restrict__ resid,
                            float* __restrict__ out) {
    __shared__ __align__(16) u16 smem[16384];    // staging 2x8192
    u16* As = smem;                              // [128][64] swizzled
    u16* Bs = smem + 8192;
    const int tid = threadIdx.x;
    // XCD swizzle: nwg=512, 64/XCD, 32 blocks (4m x 8p) per batch.
    const int id = blockIdx.x;
    const int wk = (id & 7) * 64 + (id >> 3);
    const int b  = wk >> 5;
    const int wi = wk & 31;
    const int m0 = (wi >> 3) * 128;
    const int p0 = (wi & 7) * 128;
    const int w = tid >> 6, l = tid & 63, quad = l >> 4, lm = l & 15;
    const int mo = (w >> 1) * 64, no = (w & 1) * 64;

    f32x4 acc[4][4] = {};

    const int srow = (w << 3) + (l >> 3);
    const int scc  = ((l & 7) ^ ((l >> 3) & 7)) << 3;
    const u16* wp = Wb + (size_t)(m0 + srow) * CCH + scc;
    const u16* ap = actT + (size_t)b * PP * CCH + (size_t)(p0 + srow) * CCH + scc;
    const int ldsrow = ((w << 3)) * 64;

    const int c0a = (quad ^ (lm & 7)) << 3;

    for (int k0 = 0; k0 < CCH; k0 += 64) {
        #pragma unroll
        for (int is = 0; is < 4; is++) {
            GLOAD_LDS16(wp + k0 + (size_t)(is * 32) * CCH, &As[is * 2048 + ldsrow]);
            GLOAD_LDS16(ap + k0 + (size_t)(is * 32) * CCH, &Bs[is * 2048 + ldsrow]);
        }
        __syncthreads();
        #pragma unroll
        for (int hf = 0; hf < 2; hf++) {
            const int cofs = hf ? (c0a ^ 32) : c0a;
            bf16x8 af[4], bfr[4];
            #pragma unroll
            for (int mi = 0; mi < 4; mi++)
                af[mi] = *(const bf16x8*)&As[(mo + mi*16 + lm) * 64 + cofs];
            #pragma unroll
            for (int ni = 0; ni < 4; ni++)
                bfr[ni] = *(const bf16x8*)&Bs[(no + ni*16 + lm) * 64 + cofs];
            __builtin_amdgcn_s_setprio(1);
            #pragma unroll
            for (int mi = 0; mi < 4; mi++)
                #pragma unroll
                for (int ni = 0; ni < 4; ni++)
                    acc[mi][ni] = __builtin_amdgcn_mfma_f32_16x16x32_bf16(
                        af[mi], bfr[ni], acc[mi][ni], 0, 0, 0);
            __builtin_amdgcn_s_setprio(0);
        }
        __syncthreads();
    }

    #pragma unroll
    for (int mi = 0; mi < 4; mi++) {
        f32x4 bv = *(const f32x4*)&bias[m0 + mo + mi*16 + quad*4];
        #pragma unroll
        for (int ni = 0; ni < 4; ni++) {
            int p = p0 + no + ni*16 + lm;
            #pragma unroll
            for (int r = 0; r < 4; r++) {
                int m = m0 + mo + mi*16 + quad*4 + r;
                size_t idx = ((size_t)b * CCH + m) * PP + p;
                out[idx] = acc[mi][ni][r] + bv[r] + resid[idx];
            }
        }
    }
}

// ---------------------------------------------------------------------------
extern "C" void kernel_launch(void* const* d_in, const int* in_sizes, int n_in,
                              void* d_out, int out_size, void* d_ws, size_t ws_size,
                              hipStream_t stream) {
    const float* x     = (const float*)d_in[0];
    const float* gamma = (const float*)d_in[1];
    const float* beta  = (const float*)d_in[2];
    const float* w_qkv = (const float*)d_in[3];
    const float* b_qkv = (const float*)d_in[4];
    const float* w_out = (const float*)d_in[5];
    const float* b_out = (const float*)d_in[6];

    char* ws = (char*)d_ws;
    float* ps  = (float*)ws;                    // 512 f32 partial sums
    float* pss = (float*)(ws + 2048);           // 512 f32 partial sumsq
    u16* wqb = (u16*)(ws + 4096);               // 1536*512
    u16* wob = wqb + 1536 * 512;                // 512*512
    u16* xbt = wob + 512 * 512;                 // [b][p][c]  8.4M elems
    u16* ao  = xbt + (size_t)BB * PP * CCH;     // [b][p][c]  8.4M
    u16* qTb = ao  + (size_t)BB * PP * CCH;     // [b][p][512] 8.4M
    u16* kTb = qTb + (size_t)BB * PP * CCH;     // [b][p][512] 8.4M
    u16* vb  = kTb + (size_t)BB * PP * CCH;     // [b][512][p] 8.4M  (~86 MB)

    pre_k<<<1536, 256, 0, stream>>>(x, ps, pss, w_qkv, w_out, wqb, wob);
    conv_x_k<<<dim3(16, 8, 16), 256, 0, stream>>>(x, ps, pss, gamma, beta, xbt);
    mgemm_qkv_k<<<1536, 256, 0, stream>>>(wqb, b_qkv, xbt, qTb, kTb, vb);
    fattn_k<<<512, 512, 0, stream>>>(qTb, kTb, vb, ao);
    mgemm_out_k<<<512, 256, 0, stream>>>(wob, b_out, ao, x, (float*)d_out);
}